// Round 2
// baseline (1296.223 us; speedup 1.0000x reference)
//
#include <hip/hip_runtime.h>

// B=512, V=256, W=64, H=64. Outputs: x_tilde_seq (64,512,256) fp32, h_seq (64,512,64) fp32.
// One block = 2 batches (b, b+256) processed INTERLEAVED per step (independent streams
// fill each other's barrier stalls; serial phases run on wave0(A) / wave1(B) concurrently).

#define KLOG2E  1.4426950408889634f   // log2(e)
#define K2LOG2E 2.8853900817779268f   // 2*log2(e)

__device__ __forceinline__ float frcp(float x)  { return __builtin_amdgcn_rcpf(x); }
__device__ __forceinline__ float fexp2(float x) { return __builtin_amdgcn_exp2f(x); }
__device__ __forceinline__ float fsigmoid(float x) { return frcp(1.f + fexp2(-KLOG2E * x)); }
__device__ __forceinline__ float ftanh(float x) { return 1.f - 2.f * frcp(fexp2(K2LOG2E * x) + 1.f); }

// LDS layout (float offsets)
#define L_EA   0                    // E_A[256][68] = exp(2*(u_out+b_u))
#define L_EB   17408                // E_B[256][68]
#define L_PSA  34816                // partials A [2048] (score & gates share in time)
#define L_PSB  36864                // partials B [2048]
#define L_XTA  38912                // x_tilde A [256]
#define L_XTB  39168
#define L_XSA  39424                // x_t stash A [256]
#define L_XSB  39680
#define L_EWA  39936                // e_w A [64]
#define L_EWB  40000
#define L_HCA  40064                // h||c A [128]
#define L_HCB  40192
#define L_B4   40320                // packed bias (i,f,g,o) per k [256]
#define L_TOT  40576                // = 162304 bytes

__global__ __launch_bounds__(512, 2) void enc_kernel(
    const float* __restrict__ x,     // (512,256,64)
    const float* __restrict__ w_ih,  // (256,256)
    const float* __restrict__ w_hh,  // (256,64)
    const float* __restrict__ b_ih,  // (256)
    const float* __restrict__ b_hh,  // (256)
    const float* __restrict__ w_v,   // (64)
    const float* __restrict__ w_w,   // (64,128)
    const float* __restrict__ b_w,   // (64)
    const float* __restrict__ w_u,   // (64,64)
    const float* __restrict__ b_u,   // (64)
    float* __restrict__ out_xt,      // (64,512,256)
    float* __restrict__ out_h)       // (64,512,64)
{
    extern __shared__ float lds[];
    float* EA  = lds + L_EA;   float* EB  = lds + L_EB;
    float* psA = lds + L_PSA;  float* psB = lds + L_PSB;
    float* xtA = lds + L_XTA;  float* xtB = lds + L_XTB;
    float* xsA = lds + L_XSA;  float* xsB = lds + L_XSB;
    float* ewA = lds + L_EWA;  float* ewB = lds + L_EWB;
    float* hcA = lds + L_HCA;  float* hcB = lds + L_HCB;
    float* b4  = lds + L_B4;

    const int tid  = threadIdx.x;
    const int lane = tid & 63;
    const int wvi  = tid >> 6;          // wave 0..7
    const int wq   = tid >> 5;          // w-quad 0..15 (score phase)
    const int vg   = tid & 31;          // v-group (score phase)
    const int bA   = blockIdx.x;
    const int bB   = blockIdx.x + 256;

    // ---- persistent per-thread weights ----
    // gates: thread (jg=lane, sg=wvi): 4 outputs jg+64*jj over v-slice [32*sg,32*sg+32)
    float wihr[128];
    float whhr[32];
    {
        const int jg = lane, sg = wvi;
#pragma unroll
        for (int jj = 0; jj < 4; ++jj) {
            const float4* g4 = (const float4*)(w_ih + (jg + 64*jj)*256 + sg*32);
#pragma unroll
            for (int i = 0; i < 8; ++i) {
                float4 v4 = g4[i];
                wihr[jj*32 + 4*i + 0] = v4.x; wihr[jj*32 + 4*i + 1] = v4.y;
                wihr[jj*32 + 4*i + 2] = v4.z; wihr[jj*32 + 4*i + 3] = v4.w;
            }
            const float4* h4 = (const float4*)(w_hh + (jg + 64*jj)*64 + sg*8);
#pragma unroll
            for (int i = 0; i < 2; ++i) {
                float4 v4 = h4[i];
                whhr[jj*8 + 4*i + 0] = v4.x; whhr[jj*8 + 4*i + 1] = v4.y;
                whhr[jj*8 + 4*i + 2] = v4.z; whhr[jj*8 + 4*i + 3] = v4.w;
            }
        }
    }
    // wout: lane l of wave w owns output w8 = wvi*8+(l>>3), k-slice (l&7)*16..+16
    const int w8 = wvi*8 + (lane >> 3);
    const int ks = (lane & 7) * 16;
    float4 www[4];
#pragma unroll
    for (int i = 0; i < 4; ++i) www[i] = *(const float4*)&w_w[w8*128 + ks + 4*i];
    const float bwr = b_w[w8];
    // score: -2*w_v quad (persistent)
    const float4 wvr = make_float4(-2.f*w_v[wq*4+0], -2.f*w_v[wq*4+1],
                                   -2.f*w_v[wq*4+2], -2.f*w_v[wq*4+3]);
    float Sv = 0.f;
#pragma unroll
    for (int wi = 0; wi < 64; ++wi) Sv += w_v[wi];   // uniform scalar loads

    // ---- one-time LDS fills ----
    if (tid < 64) {
        float4 bb;
        bb.x = b_ih[tid      ] + b_hh[tid      ];
        bb.y = b_ih[tid +  64] + b_hh[tid +  64];
        bb.z = b_ih[tid + 128] + b_hh[tid + 128];
        bb.w = b_ih[tid + 192] + b_hh[tid + 192];
        *(float4*)&b4[tid*4] = bb;
    }
    if (tid < 128) hcA[tid] = 0.f;
    else if (tid < 256) hcB[tid - 128] = 0.f;

    // ---- E init for both batches: E = exp(2*(x[b] @ w_u^T + b_u)) ----
    const float bu_lane = b_u[lane];
#pragma unroll 1
    for (int bb = 0; bb < 2; ++bb) {
        float* E = bb ? EB : EA;
        const int b = bb ? bB : bA;
#pragma unroll 1
        for (int half = 0; half < 2; ++half) {
            float4 wu_r[8];
#pragma unroll
            for (int i = 0; i < 8; ++i)
                wu_r[i] = *(const float4*)&w_u[lane*64 + half*32 + 4*i];
            const float* xb = x + b*16384 + half*32;
#pragma unroll 2
            for (int vi = 0; vi < 32; ++vi) {
                int v = __builtin_amdgcn_readfirstlane(wvi*32 + vi);
                const float4* xr = (const float4*)(xb + v*64);
                float acc = 0.f;
#pragma unroll
                for (int i = 0; i < 8; ++i) {
                    float4 xx = xr[i]; float4 wu = wu_r[i];
                    acc += xx.x*wu.x + xx.y*wu.y + xx.z*wu.z + xx.w*wu.w;
                }
                if (half == 0) E[v*68 + lane] = acc + bu_lane;
                else           E[v*68 + lane] = fexp2(K2LOG2E * (E[v*68 + lane] + acc));
            }
        }
    }
    __syncthreads();

    // ---- x_t quad prefetch: thread -> (batch = tid>=256 ? B : A, j = tid&255) ----
    const int xj = tid & 255;
    const float* xrow = x + (tid < 256 ? bA : bB)*16384 + xj*64;
    float4 xq_cur = *(const float4*)&xrow[0];
    float4 xq_nxt = xq_cur;

    for (int t = 0; t < 64; ++t) {
        // ---- P1: stash x_t, wout via in-wave shuffle, prefetch next x quad ----
        const int tm = t & 3;
        float xcur = (tm == 0) ? xq_cur.x : (tm == 1) ? xq_cur.y
                   : (tm == 2) ? xq_cur.z : xq_cur.w;
        if (tid < 256) xsA[xj] = xcur; else xsB[xj] = xcur;
        if (tm == 0 && t + 4 < 64) xq_nxt = *(const float4*)&xrow[t + 4];
        if (tm == 3) xq_cur = xq_nxt;

        {
            float accA = 0.f, accB = 0.f;
#pragma unroll
            for (int i = 0; i < 4; ++i) {
                float4 hA = *(const float4*)&hcA[ks + 4*i];
                float4 hB = *(const float4*)&hcB[ks + 4*i];
                float4 w4 = www[i];
                accA += hA.x*w4.x + hA.y*w4.y + hA.z*w4.z + hA.w*w4.w;
                accB += hB.x*w4.x + hB.y*w4.y + hB.z*w4.z + hB.w*w4.w;
            }
#pragma unroll
            for (int off = 1; off <= 4; off <<= 1) {
                accA += __shfl_xor(accA, off, 64);
                accB += __shfl_xor(accB, off, 64);
            }
            if ((lane & 7) == 0) {
                ewA[w8] = fexp2(K2LOG2E * (accA + bwr));
                ewB[w8] = fexp2(K2LOG2E * (accB + bwr));
            }
        }
        __syncthreads();   // B1

        // ---- P2: score partials. thread (vg, wq): v = vg+32i, w = wq*4..+4 ----
        {
            const float4 cA = *(const float4*)&ewA[wq*4];   // broadcast
            const float4 cB = *(const float4*)&ewB[wq*4];
            float sA[8], sB[8];
#pragma unroll
            for (int i = 0; i < 8; ++i) {
                const int v = vg + 32*i;
                float4 eA = *(const float4*)&EA[v*68 + wq*4];
                float4 eB = *(const float4*)&EB[v*68 + wq*4];
                sA[i] = wvr.x*frcp(eA.x*cA.x + 1.f) + wvr.y*frcp(eA.y*cA.y + 1.f)
                      + wvr.z*frcp(eA.z*cA.z + 1.f) + wvr.w*frcp(eA.w*cA.w + 1.f);
                sB[i] = wvr.x*frcp(eB.x*cB.x + 1.f) + wvr.y*frcp(eB.y*cB.y + 1.f)
                      + wvr.z*frcp(eB.z*cB.z + 1.f) + wvr.w*frcp(eB.w*cB.w + 1.f);
            }
#pragma unroll
            for (int i = 0; i < 8; ++i) {
                sA[i] += __shfl_xor(sA[i], 32, 64);
                sB[i] += __shfl_xor(sB[i], 32, 64);
            }
            if (lane < 32) {
#pragma unroll
                for (int i = 0; i < 8; ++i) {
                    psA[wvi*256 + i*32 + vg] = sA[i];
                    psB[wvi*256 + i*32 + vg] = sB[i];
                }
            }
        }
        __syncthreads();   // B2

        // ---- P3: softmax + x_tilde. wave0 = A, wave1 = B ----
        if (wvi < 2) {
            float* ps = wvi ? psB : psA;
            float* xs = wvi ? xsB : xsA;
            float* xt = wvi ? xtB : xtA;
            float* o  = out_xt + t*131072 + (wvi ? bB : bA)*256;
            float4 s = make_float4(Sv, Sv, Sv, Sv);
#pragma unroll
            for (int w = 0; w < 8; ++w) {
                float4 p = *(const float4*)&ps[w*256 + 4*lane];
                s.x += p.x; s.y += p.y; s.z += p.z; s.w += p.w;
            }
            float4 e;
            e.x = fexp2(KLOG2E*s.x); e.y = fexp2(KLOG2E*s.y);
            e.z = fexp2(KLOG2E*s.z); e.w = fexp2(KLOG2E*s.w);
            float sum = (e.x + e.y) + (e.z + e.w);
#pragma unroll
            for (int off = 1; off <= 32; off <<= 1) sum += __shfl_xor(sum, off, 64);
            float r = frcp(sum);
            float4 x4 = *(const float4*)&xs[4*lane];
            float4 xo;
            xo.x = e.x*r*x4.x; xo.y = e.y*r*x4.y; xo.z = e.z*r*x4.z; xo.w = e.w*r*x4.w;
            *(float4*)&xt[4*lane] = xo;
            *(float4*)&o[4*lane] = xo;
        }
        __syncthreads();   // B3

        // ---- P4: gates partials (both batches), packed (i,f,g,o) writes ----
        {
            const int sg = wvi, jg = lane;
            float a0=0.f,a1=0.f,a2=0.f,a3=0.f, c0=0.f,c1=0.f,c2=0.f,c3=0.f;
            const float4* xA4 = (const float4*)(xtA + sg*32);
            const float4* xB4 = (const float4*)(xtB + sg*32);
#pragma unroll
            for (int i = 0; i < 8; ++i) {
                float4 xa = xA4[i], xb = xB4[i];
                a0 += xa.x*wihr[   4*i] + xa.y*wihr[   4*i+1] + xa.z*wihr[   4*i+2] + xa.w*wihr[   4*i+3];
                a1 += xa.x*wihr[32+4*i] + xa.y*wihr[32+4*i+1] + xa.z*wihr[32+4*i+2] + xa.w*wihr[32+4*i+3];
                a2 += xa.x*wihr[64+4*i] + xa.y*wihr[64+4*i+1] + xa.z*wihr[64+4*i+2] + xa.w*wihr[64+4*i+3];
                a3 += xa.x*wihr[96+4*i] + xa.y*wihr[96+4*i+1] + xa.z*wihr[96+4*i+2] + xa.w*wihr[96+4*i+3];
                c0 += xb.x*wihr[   4*i] + xb.y*wihr[   4*i+1] + xb.z*wihr[   4*i+2] + xb.w*wihr[   4*i+3];
                c1 += xb.x*wihr[32+4*i] + xb.y*wihr[32+4*i+1] + xb.z*wihr[32+4*i+2] + xb.w*wihr[32+4*i+3];
                c2 += xb.x*wihr[64+4*i] + xb.y*wihr[64+4*i+1] + xb.z*wihr[64+4*i+2] + xb.w*wihr[64+4*i+3];
                c3 += xb.x*wihr[96+4*i] + xb.y*wihr[96+4*i+1] + xb.z*wihr[96+4*i+2] + xb.w*wihr[96+4*i+3];
            }
            const float4* hA4 = (const float4*)(hcA + sg*8);
            const float4* hB4 = (const float4*)(hcB + sg*8);
#pragma unroll
            for (int i = 0; i < 2; ++i) {
                float4 ha = hA4[i], hb = hB4[i];
                a0 += ha.x*whhr[   4*i] + ha.y*whhr[   4*i+1] + ha.z*whhr[   4*i+2] + ha.w*whhr[   4*i+3];
                a1 += ha.x*whhr[ 8+4*i] + ha.y*whhr[ 8+4*i+1] + ha.z*whhr[ 8+4*i+2] + ha.w*whhr[ 8+4*i+3];
                a2 += ha.x*whhr[16+4*i] + ha.y*whhr[16+4*i+1] + ha.z*whhr[16+4*i+2] + ha.w*whhr[16+4*i+3];
                a3 += ha.x*whhr[24+4*i] + ha.y*whhr[24+4*i+1] + ha.z*whhr[24+4*i+2] + ha.w*whhr[24+4*i+3];
                c0 += hb.x*whhr[   4*i] + hb.y*whhr[   4*i+1] + hb.z*whhr[   4*i+2] + hb.w*whhr[   4*i+3];
                c1 += hb.x*whhr[ 8+4*i] + hb.y*whhr[ 8+4*i+1] + hb.z*whhr[ 8+4*i+2] + hb.w*whhr[ 8+4*i+3];
                c2 += hb.x*whhr[16+4*i] + hb.y*whhr[16+4*i+1] + hb.z*whhr[16+4*i+2] + hb.w*whhr[16+4*i+3];
                c3 += hb.x*whhr[24+4*i] + hb.y*whhr[24+4*i+1] + hb.z*whhr[24+4*i+2] + hb.w*whhr[24+4*i+3];
            }
            *(float4*)&psA[sg*256 + jg*4] = make_float4(a0, a1, a2, a3);
            *(float4*)&psB[sg*256 + jg*4] = make_float4(c0, c1, c2, c3);
        }
        __syncthreads();   // B4

        // ---- P5: LSTM cell. wave0 = A, wave1 = B ----
        if (wvi < 2) {
            float* ps = wvi ? psB : psA;
            float* hc = wvi ? hcB : hcA;
            float* oh = out_h + t*32768 + (wvi ? bB : bA)*64;
            const int k = lane;
            float4 g = *(const float4*)&b4[4*k];
#pragma unroll
            for (int s = 0; s < 8; ++s) {
                float4 p = *(const float4*)&ps[s*256 + 4*k];
                g.x += p.x; g.y += p.y; g.z += p.z; g.w += p.w;
            }
            float gi = fsigmoid(g.x), gf = fsigmoid(g.y);
            float gg = ftanh(g.z),    go = fsigmoid(g.w);
            float cn = gf * hc[64 + k] + gi * gg;
            float hn = go * ftanh(cn);
            hc[k] = hn; hc[64 + k] = cn;
            oh[k] = hn;
        }
        __syncthreads();   // B5
    }
}

extern "C" void kernel_launch(void* const* d_in, const int* in_sizes, int n_in,
                              void* d_out, int out_size, void* d_ws, size_t ws_size,
                              hipStream_t stream) {
    const float* x    = (const float*)d_in[0];
    const float* w_ih = (const float*)d_in[1];
    const float* w_hh = (const float*)d_in[2];
    const float* b_ih = (const float*)d_in[3];
    const float* b_hh = (const float*)d_in[4];
    const float* w_v  = (const float*)d_in[5];
    const float* w_w  = (const float*)d_in[6];
    const float* b_w  = (const float*)d_in[7];
    const float* w_u  = (const float*)d_in[8];
    const float* b_u  = (const float*)d_in[9];

    float* out_xt = (float*)d_out;
    float* out_h  = out_xt + 64*512*256;

    const size_t shbytes = (size_t)L_TOT * sizeof(float);  // 162304 B
    hipFuncSetAttribute((const void*)enc_kernel,
                        hipFuncAttributeMaxDynamicSharedMemorySize, (int)shbytes);
    enc_kernel<<<dim3(256), dim3(512), shbytes, stream>>>(
        x, w_ih, w_hh, b_ih, b_hh, w_v, w_w, b_w, w_u, b_u, out_xt, out_h);
}

// Round 3
// 541.139 us; speedup vs baseline: 2.3954x; 2.3954x over previous
//
#include <hip/hip_runtime.h>

// B=512, V=256, W=64, H=64. Outputs: x_tilde_seq (64,512,256) fp32, h_seq (64,512,64) fp32.
// One block = 2 batches (b, b+256) INTERLEAVED per step. 512 threads, 1 block/CU.
// __launch_bounds__(512,1): VGPR cap 256 so w_ih/w_hh stay truly register-resident
// (512 threads x 128 floats = exactly the 256KB of w_ih, no duplication).

#define KLOG2E  1.4426950408889634f   // log2(e)
#define K2LOG2E 2.8853900817779268f   // 2*log2(e)

__device__ __forceinline__ float frcp(float x)  { return __builtin_amdgcn_rcpf(x); }
__device__ __forceinline__ float fexp2(float x) { return __builtin_amdgcn_exp2f(x); }
__device__ __forceinline__ float fsigmoid(float x) { return frcp(1.f + fexp2(-KLOG2E * x)); }
__device__ __forceinline__ float ftanh(float x) { return 1.f - 2.f * frcp(fexp2(K2LOG2E * x) + 1.f); }

// LDS layout (float offsets)
#define L_EA   0                    // E_A[256][68] = exp(2*(u_out+b_u))
#define L_EB   17408                // E_B[256][68]
#define L_PSA  34816                // partials A [2048] (score & gates share in time)
#define L_PSB  36864                // partials B [2048]
#define L_XTA  38912                // x_tilde A [256]
#define L_XTB  39168
#define L_XSA  39424                // x_t stash A [256]
#define L_XSB  39680
#define L_EWA  39936                // e_w A [64]
#define L_EWB  40000
#define L_HCA  40064                // h||c A [128]
#define L_HCB  40192
#define L_BI   40320                // bias b_ih+b_hh [256] (gate-major, q*64+k)
#define L_TOT  40576                // 162304 bytes

__global__ __launch_bounds__(512, 1) void enc_kernel(
    const float* __restrict__ x,     // (512,256,64)
    const float* __restrict__ w_ih,  // (256,256)
    const float* __restrict__ w_hh,  // (256,64)
    const float* __restrict__ b_ih,  // (256)
    const float* __restrict__ b_hh,  // (256)
    const float* __restrict__ w_v,   // (64)
    const float* __restrict__ w_w,   // (64,128)
    const float* __restrict__ b_w,   // (64)
    const float* __restrict__ w_u,   // (64,64)
    const float* __restrict__ b_u,   // (64)
    float* __restrict__ out_xt,      // (64,512,256)
    float* __restrict__ out_h)       // (64,512,64)
{
    extern __shared__ float lds[];
    float* EA  = lds + L_EA;   float* EB  = lds + L_EB;
    float* psA = lds + L_PSA;  float* psB = lds + L_PSB;
    float* xtA = lds + L_XTA;  float* xtB = lds + L_XTB;
    float* xsA = lds + L_XSA;  float* xsB = lds + L_XSB;
    float* ewA = lds + L_EWA;  float* ewB = lds + L_EWB;
    float* hcA = lds + L_HCA;  float* hcB = lds + L_HCB;
    float* biasL = lds + L_BI;

    const int tid  = threadIdx.x;
    const int lane = tid & 63;
    const int wvi  = tid >> 6;          // wave 0..7
    const int wq   = tid >> 5;          // w-quad 0..15 (score phase)
    const int vg   = tid & 31;          // v-group (score phase)
    const int bA   = blockIdx.x;
    const int bB   = blockIdx.x + 256;

    // ---- persistent per-thread weights ----
    // gates: thread (jg=lane, sg=wvi): outputs q*64+jg (q=0..3) over v-slice [32*sg,32*sg+32)
    float wihr[128];
    float whhr[32];
    {
        const int jg = lane, sg = wvi;
#pragma unroll
        for (int jj = 0; jj < 4; ++jj) {
            const float4* g4 = (const float4*)(w_ih + (jg + 64*jj)*256 + sg*32);
#pragma unroll
            for (int i = 0; i < 8; ++i) {
                float4 v4 = g4[i];
                wihr[jj*32 + 4*i + 0] = v4.x; wihr[jj*32 + 4*i + 1] = v4.y;
                wihr[jj*32 + 4*i + 2] = v4.z; wihr[jj*32 + 4*i + 3] = v4.w;
            }
            const float4* h4 = (const float4*)(w_hh + (jg + 64*jj)*64 + sg*8);
#pragma unroll
            for (int i = 0; i < 2; ++i) {
                float4 v4 = h4[i];
                whhr[jj*8 + 4*i + 0] = v4.x; whhr[jj*8 + 4*i + 1] = v4.y;
                whhr[jj*8 + 4*i + 2] = v4.z; whhr[jj*8 + 4*i + 3] = v4.w;
            }
        }
    }
    // wout: lane l of wave w owns output w8 = wvi*8+(l>>3), k-slice (l&7)*16..+16
    const int w8 = wvi*8 + (lane >> 3);
    const int ks = (lane & 7) * 16;
    float4 www[4];
#pragma unroll
    for (int i = 0; i < 4; ++i) www[i] = *(const float4*)&w_w[w8*128 + ks + 4*i];
    const float bwr = b_w[w8];
    // score: -2*w_v quad (persistent)
    const float4 wvr = make_float4(-2.f*w_v[wq*4+0], -2.f*w_v[wq*4+1],
                                   -2.f*w_v[wq*4+2], -2.f*w_v[wq*4+3]);
    float Sv = 0.f;
#pragma unroll
    for (int wi = 0; wi < 64; ++wi) Sv += w_v[wi];   // uniform scalar loads

    // ---- one-time LDS fills ----
    if (tid < 256) biasL[tid] = b_ih[tid] + b_hh[tid];
    if (tid < 128) hcA[tid] = 0.f;
    else if (tid < 256) hcB[tid - 128] = 0.f;

    // ---- E init for both batches: E = exp(2*(x[b] @ w_u^T + b_u)) ----
    const float bu_lane = b_u[lane];
#pragma unroll 1
    for (int bb = 0; bb < 2; ++bb) {
        float* E = bb ? EB : EA;
        const int b = bb ? bB : bA;
#pragma unroll 1
        for (int half = 0; half < 2; ++half) {
            float4 wu_r[8];
#pragma unroll
            for (int i = 0; i < 8; ++i)
                wu_r[i] = *(const float4*)&w_u[lane*64 + half*32 + 4*i];
            const float* xb = x + b*16384 + half*32;
#pragma unroll 2
            for (int vi = 0; vi < 32; ++vi) {
                int v = __builtin_amdgcn_readfirstlane(wvi*32 + vi);
                const float4* xr = (const float4*)(xb + v*64);
                float acc = 0.f;
#pragma unroll
                for (int i = 0; i < 8; ++i) {
                    float4 xx = xr[i]; float4 wu = wu_r[i];
                    acc += xx.x*wu.x + xx.y*wu.y + xx.z*wu.z + xx.w*wu.w;
                }
                if (half == 0) E[v*68 + lane] = acc + bu_lane;
                else           E[v*68 + lane] = fexp2(K2LOG2E * (E[v*68 + lane] + acc));
            }
        }
    }
    __syncthreads();

    // ---- x_t quad prefetch: thread -> (batch = tid>=256 ? B : A, j = tid&255) ----
    const int xj = tid & 255;
    const float* xrow = x + (tid < 256 ? bA : bB)*16384 + xj*64;
    float4 xq_cur = *(const float4*)&xrow[0];
    float4 xq_nxt = xq_cur;

    for (int t = 0; t < 64; ++t) {
        // ---- P1: stash x_t; wout via in-wave shuffle; prefetch next x quad ----
        const int tm = t & 3;
        float xcur = (tm == 0) ? xq_cur.x : (tm == 1) ? xq_cur.y
                   : (tm == 2) ? xq_cur.z : xq_cur.w;
        if (tid < 256) xsA[xj] = xcur; else xsB[xj] = xcur;
        if (tm == 0 && t + 4 < 64) xq_nxt = *(const float4*)&xrow[t + 4];
        if (tm == 3) xq_cur = xq_nxt;

        {
            float accA = 0.f, accB = 0.f;
#pragma unroll
            for (int i = 0; i < 4; ++i) {
                float4 hA = *(const float4*)&hcA[ks + 4*i];
                float4 hB = *(const float4*)&hcB[ks + 4*i];
                float4 w4 = www[i];
                accA += hA.x*w4.x + hA.y*w4.y + hA.z*w4.z + hA.w*w4.w;
                accB += hB.x*w4.x + hB.y*w4.y + hB.z*w4.z + hB.w*w4.w;
            }
#pragma unroll
            for (int off = 1; off <= 4; off <<= 1) {
                accA += __shfl_xor(accA, off, 64);
                accB += __shfl_xor(accB, off, 64);
            }
            if ((lane & 7) == 0) {
                ewA[w8] = fexp2(K2LOG2E * (accA + bwr));
                ewB[w8] = fexp2(K2LOG2E * (accB + bwr));
            }
        }
        __syncthreads();   // B1

        // ---- P2: score partials. thread (vg, wq): v = vg+32i, w = wq*4..+4 ----
        {
            const float4 cA = *(const float4*)&ewA[wq*4];   // broadcast
            const float4 cB = *(const float4*)&ewB[wq*4];
            float sA[8], sB[8];
#pragma unroll
            for (int i = 0; i < 8; ++i) {
                const int v = vg + 32*i;
                float4 eA = *(const float4*)&EA[v*68 + wq*4];
                float4 eB = *(const float4*)&EB[v*68 + wq*4];
                sA[i] = wvr.x*frcp(eA.x*cA.x + 1.f) + wvr.y*frcp(eA.y*cA.y + 1.f)
                      + wvr.z*frcp(eA.z*cA.z + 1.f) + wvr.w*frcp(eA.w*cA.w + 1.f);
                sB[i] = wvr.x*frcp(eB.x*cB.x + 1.f) + wvr.y*frcp(eB.y*cB.y + 1.f)
                      + wvr.z*frcp(eB.z*cB.z + 1.f) + wvr.w*frcp(eB.w*cB.w + 1.f);
            }
            // combine the two w-quads living in lane l / l^32, then:
            // lanes 0-31 store batch A partials, lanes 32-63 store batch B.
            float* pdst = (lane < 32) ? psA : psB;
#pragma unroll
            for (int i = 0; i < 8; ++i) {
                sA[i] += __shfl_xor(sA[i], 32, 64);
                sB[i] += __shfl_xor(sB[i], 32, 64);
                pdst[wvi*256 + i*32 + vg] = (lane < 32) ? sA[i] : sB[i];
            }
        }
        __syncthreads();   // B2

        // ---- P3: softmax + x_tilde. wave0 = A, wave1 = B (scalar stride-1 LDS) ----
        if (wvi < 2) {
            float* ps = wvi ? psB : psA;
            float* xs = wvi ? xsB : xsA;
            float* xt = wvi ? xtB : xtA;
            float* o  = out_xt + t*131072 + (wvi ? bB : bA)*256;
            float s0 = Sv, s1 = Sv, s2 = Sv, s3 = Sv;
#pragma unroll
            for (int w = 0; w < 8; ++w) {
                s0 += ps[w*256 + lane      ];
                s1 += ps[w*256 + lane +  64];
                s2 += ps[w*256 + lane + 128];
                s3 += ps[w*256 + lane + 192];
            }
            float e0 = fexp2(KLOG2E*s0), e1 = fexp2(KLOG2E*s1);
            float e2 = fexp2(KLOG2E*s2), e3 = fexp2(KLOG2E*s3);
            float sum = (e0 + e1) + (e2 + e3);
#pragma unroll
            for (int off = 1; off <= 32; off <<= 1) sum += __shfl_xor(sum, off, 64);
            float r = frcp(sum);
            float t0 = e0*r*xs[lane      ];
            float t1 = e1*r*xs[lane +  64];
            float t2 = e2*r*xs[lane + 128];
            float t3 = e3*r*xs[lane + 192];
            xt[lane      ] = t0; xt[lane +  64] = t1;
            xt[lane + 128] = t2; xt[lane + 192] = t3;
            o[lane      ] = t0; o[lane +  64] = t1;
            o[lane + 128] = t2; o[lane + 192] = t3;
        }
        __syncthreads();   // B3

        // ---- P4: gates partials (both batches), scalar stride-1 stores ----
        {
            const int sg = wvi, jg = lane;
            float a0=0.f,a1=0.f,a2=0.f,a3=0.f, c0=0.f,c1=0.f,c2=0.f,c3=0.f;
            const float4* xA4 = (const float4*)(xtA + sg*32);
            const float4* xB4 = (const float4*)(xtB + sg*32);
#pragma unroll
            for (int i = 0; i < 8; ++i) {
                float4 xa = xA4[i], xb = xB4[i];
                a0 += xa.x*wihr[   4*i] + xa.y*wihr[   4*i+1] + xa.z*wihr[   4*i+2] + xa.w*wihr[   4*i+3];
                a1 += xa.x*wihr[32+4*i] + xa.y*wihr[32+4*i+1] + xa.z*wihr[32+4*i+2] + xa.w*wihr[32+4*i+3];
                a2 += xa.x*wihr[64+4*i] + xa.y*wihr[64+4*i+1] + xa.z*wihr[64+4*i+2] + xa.w*wihr[64+4*i+3];
                a3 += xa.x*wihr[96+4*i] + xa.y*wihr[96+4*i+1] + xa.z*wihr[96+4*i+2] + xa.w*wihr[96+4*i+3];
                c0 += xb.x*wihr[   4*i] + xb.y*wihr[   4*i+1] + xb.z*wihr[   4*i+2] + xb.w*wihr[   4*i+3];
                c1 += xb.x*wihr[32+4*i] + xb.y*wihr[32+4*i+1] + xb.z*wihr[32+4*i+2] + xb.w*wihr[32+4*i+3];
                c2 += xb.x*wihr[64+4*i] + xb.y*wihr[64+4*i+1] + xb.z*wihr[64+4*i+2] + xb.w*wihr[64+4*i+3];
                c3 += xb.x*wihr[96+4*i] + xb.y*wihr[96+4*i+1] + xb.z*wihr[96+4*i+2] + xb.w*wihr[96+4*i+3];
            }
            const float4* hA4 = (const float4*)(hcA + sg*8);
            const float4* hB4 = (const float4*)(hcB + sg*8);
#pragma unroll
            for (int i = 0; i < 2; ++i) {
                float4 ha = hA4[i], hb = hB4[i];
                a0 += ha.x*whhr[   4*i] + ha.y*whhr[   4*i+1] + ha.z*whhr[   4*i+2] + ha.w*whhr[   4*i+3];
                a1 += ha.x*whhr[ 8+4*i] + ha.y*whhr[ 8+4*i+1] + ha.z*whhr[ 8+4*i+2] + ha.w*whhr[ 8+4*i+3];
                a2 += ha.x*whhr[16+4*i] + ha.y*whhr[16+4*i+1] + ha.z*whhr[16+4*i+2] + ha.w*whhr[16+4*i+3];
                a3 += ha.x*whhr[24+4*i] + ha.y*whhr[24+4*i+1] + ha.z*whhr[24+4*i+2] + ha.w*whhr[24+4*i+3];
                c0 += hb.x*whhr[   4*i] + hb.y*whhr[   4*i+1] + hb.z*whhr[   4*i+2] + hb.w*whhr[   4*i+3];
                c1 += hb.x*whhr[ 8+4*i] + hb.y*whhr[ 8+4*i+1] + hb.z*whhr[ 8+4*i+2] + hb.w*whhr[ 8+4*i+3];
                c2 += hb.x*whhr[16+4*i] + hb.y*whhr[16+4*i+1] + hb.z*whhr[16+4*i+2] + hb.w*whhr[16+4*i+3];
                c3 += hb.x*whhr[24+4*i] + hb.y*whhr[24+4*i+1] + hb.z*whhr[24+4*i+2] + hb.w*whhr[24+4*i+3];
            }
            psA[sg*256 + jg      ] = a0;
            psA[sg*256 + jg +  64] = a1;
            psA[sg*256 + jg + 128] = a2;
            psA[sg*256 + jg + 192] = a3;
            psB[sg*256 + jg      ] = c0;
            psB[sg*256 + jg +  64] = c1;
            psB[sg*256 + jg + 128] = c2;
            psB[sg*256 + jg + 192] = c3;
        }
        __syncthreads();   // B4

        // ---- P5: LSTM cell. wave0 = A, wave1 = B (scalar stride-1 LDS) ----
        if (wvi < 2) {
            float* ps = wvi ? psB : psA;
            float* hc = wvi ? hcB : hcA;
            float* oh = out_h + t*32768 + (wvi ? bB : bA)*64;
            const int k = lane;
            float gi = biasL[k], gf = biasL[64+k], gg = biasL[128+k], go = biasL[192+k];
#pragma unroll
            for (int s = 0; s < 8; ++s) {
                gi += ps[s*256 + k      ];
                gf += ps[s*256 + k +  64];
                gg += ps[s*256 + k + 128];
                go += ps[s*256 + k + 192];
            }
            gi = fsigmoid(gi); gf = fsigmoid(gf);
            gg = ftanh(gg);    go = fsigmoid(go);
            float cn = gf * hc[64 + k] + gi * gg;
            float hn = go * ftanh(cn);
            hc[k] = hn; hc[64 + k] = cn;
            oh[k] = hn;
        }
        __syncthreads();   // B5
    }
}

extern "C" void kernel_launch(void* const* d_in, const int* in_sizes, int n_in,
                              void* d_out, int out_size, void* d_ws, size_t ws_size,
                              hipStream_t stream) {
    const float* x    = (const float*)d_in[0];
    const float* w_ih = (const float*)d_in[1];
    const float* w_hh = (const float*)d_in[2];
    const float* b_ih = (const float*)d_in[3];
    const float* b_hh = (const float*)d_in[4];
    const float* w_v  = (const float*)d_in[5];
    const float* w_w  = (const float*)d_in[6];
    const float* b_w  = (const float*)d_in[7];
    const float* w_u  = (const float*)d_in[8];
    const float* b_u  = (const float*)d_in[9];

    float* out_xt = (float*)d_out;
    float* out_h  = out_xt + 64*512*256;

    const size_t shbytes = (size_t)L_TOT * sizeof(float);  // 162304 B
    hipFuncSetAttribute((const void*)enc_kernel,
                        hipFuncAttributeMaxDynamicSharedMemorySize, (int)shbytes);
    enc_kernel<<<dim3(256), dim3(512), shbytes, stream>>>(
        x, w_ih, w_hh, b_ih, b_hh, w_v, w_w, b_w, w_u, b_u, out_xt, out_h);
}